// Round 9
// baseline (154.394 us; speedup 1.0000x reference)
//
#include <hip/hip_runtime.h>
#include <hip/hip_bf16.h>

// Problem constants
#define BB     32
#define HIDD   128
#define ATT    128
#define SS     8192            // T*N positions per batch
#define BLKPB  32              // blocks per batch (256 rows each)
#define PART_STRIDE 132        // [m, l, pad, pad, acc[128]] (16B-aligned acc)
#define PART_BYTES (BB * BLKPB * PART_STRIDE * 4)

typedef float f32x4 __attribute__((ext_vector_type(4)));
typedef short s16x8 __attribute__((ext_vector_type(8)));

__device__ inline float bf2f(unsigned short h) {
    return __uint_as_float(((unsigned)h) << 16);
}
__device__ inline float fast_tanh(float x) {
    x = fminf(15.f, fmaxf(-15.f, x));
    float e2 = __expf(2.f * x);
    return (e2 - 1.f) * __builtin_amdgcn_rcpf(e2 + 1.f);
}
__device__ inline unsigned cvt_pk_bf16(float a, float b) {
    unsigned r;
    asm("v_cvt_pk_bf16_f32 %0, %1, %2" : "=v"(r) : "v"(a), "v"(b));
    return r;   // low16 = bf16(a), high16 = bf16(b)
}

// ---- single fused kernel ----
// Per block (b, blk): stage W f32->bf16 into LDS + compute bias2[b] locally
// (hidden under H tile-0 HBM latency), then the proven zero-barrier main loop:
// each wave owns 64 rows (4 tiles of 16), single raw[8] prefetch buffer,
// swapped MFMA vs W, in-lane v-dot, online softmax, accum from the same regs.
// Epilogue: block partial -> global; last block per batch combines.
// NOTE __launch_bounds__(256, 2): 2nd-arg VGPR cap is 256/arg on this backend
// (R4 arg2->128 ok; R5-7 arg4->64 + catastrophic spill).
__global__ __launch_bounds__(256, 2) void attn_fused_kernel(
    const float* __restrict__ hist,
    const float* __restrict__ cur,
    const float* __restrict__ whw,
    const float* __restrict__ wxw,
    const float* __restrict__ wxb,
    const float* __restrict__ whb,
    const float* __restrict__ vw,
    float* __restrict__ partials,
    int* __restrict__ cnt,
    float* __restrict__ out)
{
    __shared__ __align__(16) unsigned short sW[ATT * HIDD];  // 32 KB bf16, swizzled
    __shared__ float sB[ATT];
    __shared__ float sV[ATT];
    __shared__ float sC[HIDD];
    __shared__ float sBp[2][ATT];
    __shared__ float sAccW[4][HIDD];   // per-wave merged output
    __shared__ float sML[4][2];
    __shared__ int   sLast;

    const int tid  = threadIdx.x;
    const int bid  = blockIdx.x;
    const int b    = bid >> 5;          // /BLKPB
    const int blk  = bid & 31;
    const int lane = tid & 63;
    const int wid  = tid >> 6;
    const int l15  = lane & 15;
    const int lg   = lane >> 4;

    // wave's 64 rows
    const float* srcw = hist + ((size_t)b * SS + (size_t)blk * 256 + wid * 64) * HIDD;

    f32x4 raw[8];   // single in-flight tile (16 rows x 128 f32 / 64 lanes)
    auto issue = [&](int t) {
        const float* r = srcw + (size_t)(t * 16 + l15) * HIDD + lg * 8;
#pragma unroll
        for (int kk = 0; kk < 4; ++kk) {
            raw[2 * kk]     = *(const f32x4*)(r + kk * 32);
            raw[2 * kk + 1] = *(const f32x4*)(r + kk * 32 + 4);
        }
        __builtin_amdgcn_sched_barrier(0);   // pin issue point
    };

    issue(0);   // H tile-0 loads first: HBM head start

    // ---- stage W f32 -> bf16 (swizzled) ----
#pragma unroll
    for (int i = 0; i < 8; ++i) {
        int e = (i * 256 + tid) * 8;       // u16 index
        int row = e >> 7;
        f32x4 w0 = *(const f32x4*)(whw + e);
        f32x4 w1 = *(const f32x4*)(whw + e + 4);
        union { s16x8 v; unsigned w[4]; } o;
        o.w[0] = cvt_pk_bf16(w0.x, w0.y);
        o.w[1] = cvt_pk_bf16(w0.z, w0.w);
        o.w[2] = cvt_pk_bf16(w1.x, w1.y);
        o.w[3] = cvt_pk_bf16(w1.z, w1.w);
        *(s16x8*)&sW[e ^ ((row & 7) << 3)] = o.v;
    }
    if (tid < HIDD) { sC[tid] = cur[b * HIDD + tid]; sV[tid] = vw[tid]; }
    __syncthreads();

    // ---- bias2[b][a] = Wh_b + Wx_b + cur_h[b,:].Wx_w[a,:] (split over 2 halves) ----
    {
        const int a = tid & 127, half = tid >> 7;
        float d = 0.f;
#pragma unroll
        for (int hh = 0; hh < 16; ++hh) {
            f32x4 x = *(const f32x4*)(wxw + a * HIDD + half * 64 + hh * 4);
            f32x4 c = *(const f32x4*)&sC[half * 64 + hh * 4];
            d += x.x * c.x + x.y * c.y + x.z * c.z + x.w * c.w;
        }
        sBp[half][a] = d;
    }
    __syncthreads();
    if (tid < ATT) sB[tid] = sBp[0][tid] + sBp[1][tid] + wxb[tid] + whb[tid];
    __syncthreads();

    float m_run = -1e30f, l_run = 0.f;
    f32x4 acc[8];
#pragma unroll
    for (int q = 0; q < 8; ++q) acc[q] = (f32x4){0.f, 0.f, 0.f, 0.f};

#pragma unroll
    for (int t = 0; t < 4; ++t) {
        // ---- cvt raw -> bf16 frags (auto-waits this tile's loads) ----
        s16x8 hfrag[4];
#pragma unroll
        for (int kk = 0; kk < 4; ++kk) {
            union { s16x8 v; unsigned w[4]; } fr;
            fr.w[0] = cvt_pk_bf16(raw[2 * kk].x,     raw[2 * kk].y);
            fr.w[1] = cvt_pk_bf16(raw[2 * kk].z,     raw[2 * kk].w);
            fr.w[2] = cvt_pk_bf16(raw[2 * kk + 1].x, raw[2 * kk + 1].y);
            fr.w[3] = cvt_pk_bf16(raw[2 * kk + 1].z, raw[2 * kk + 1].w);
            hfrag[kk] = fr.v;
        }
        // ---- re-issue next tile into the SAME raw regs (async) ----
        if (t < 3) issue(t + 1);

        // ---- scores: 8 a-tiles, D[a][s] = W . H^T, v-dot in-lane ----
        float p = 0.f;
#pragma unroll
        for (int at = 0; at < 8; ++at) {
            s16x8 wfrag[4];
#pragma unroll
            for (int kk = 0; kk < 4; ++kk) {
                int idx = ((at * 16 + l15) * HIDD + kk * 32 + lg * 8) ^ ((l15 & 7) << 3);
                wfrag[kk] = *(const s16x8*)&sW[idx];
            }
            f32x4 d = {0.f, 0.f, 0.f, 0.f};
#pragma unroll
            for (int kk = 0; kk < 4; ++kk)
                d = __builtin_amdgcn_mfma_f32_16x16x32_bf16(wfrag[kk], hfrag[kk], d, 0, 0, 0);
            f32x4 bb = *(const f32x4*)&sB[at * 16 + lg * 4];
            f32x4 vx = *(const f32x4*)&sV[at * 16 + lg * 4];
#pragma unroll
            for (int r = 0; r < 4; ++r)
                p += vx[r] * fast_tanh(d[r] + bb[r]);
        }
        p += __shfl_xor(p, 16, 64);
        p += __shfl_xor(p, 32, 64);   // all lanes: score for row = l15

        // ---- online softmax over this tile's 16 rows ----
        float mx = p;
#pragma unroll
        for (int m = 1; m < 16; m <<= 1) mx = fmaxf(mx, __shfl_xor(mx, m, 64));
        float m_new = fmaxf(m_run, mx);
        float so = __expf(m_run - m_new);
        float ev = __expf(p - m_new);
        float es = ev;
#pragma unroll
        for (int m = 1; m < 16; m <<= 1) es += __shfl_xor(es, m, 64);
        l_run = l_run * so + es;
        m_run = m_new;

        // ---- weighted accumulation from the SAME frags (H touched once) ----
#pragma unroll
        for (int q = 0; q < 8; ++q) acc[q] *= so;
#pragma unroll
        for (int kk = 0; kk < 4; ++kk) {
            union { s16x8 v; unsigned short u[8]; } fr; fr.v = hfrag[kk];
#pragma unroll
            for (int i = 0; i < 4; ++i) acc[2 * kk][i]     += ev * bf2f(fr.u[i]);
#pragma unroll
            for (int i = 0; i < 4; ++i) acc[2 * kk + 1][i] += ev * bf2f(fr.u[4 + i]);
        }
    }

    // ---- reduce acc over the 16 s-lanes (within each 16-lane group) ----
#pragma unroll
    for (int m = 1; m < 16; m <<= 1) {
#pragma unroll
        for (int q = 0; q < 8; ++q) {
#pragma unroll
            for (int i = 0; i < 4; ++i)
                acc[q][i] += __shfl_xor(acc[q][i], m, 64);
        }
    }
    // lanes l15==0 (lg = 0..3) hold h[k] for k = kk*32 + lg*8 + i
    if (l15 == 0) {
#pragma unroll
        for (int kk = 0; kk < 4; ++kk) {
            *(f32x4*)&sAccW[wid][kk * 32 + lg * 8]     = acc[2 * kk];
            *(f32x4*)&sAccW[wid][kk * 32 + lg * 8 + 4] = acc[2 * kk + 1];
        }
    }
    if (lane == 0) { sML[wid][0] = m_run; sML[wid][1] = l_run; }
    __syncthreads();

    // ---- merge 4 waves, write block partial ----
    float* part = partials + (size_t)(b * BLKPB + blk) * PART_STRIDE;
    if (tid < HIDD) {
        float M = fmaxf(fmaxf(sML[0][0], sML[1][0]), fmaxf(sML[2][0], sML[3][0]));
        float num = 0.f, den = 0.f;
#pragma unroll
        for (int w = 0; w < 4; ++w) {
            float sc = __expf(sML[w][0] - M);
            den += sML[w][1] * sc;
            num += sAccW[w][tid] * sc;
        }
        part[4 + tid] = num;
        if (tid == 0) { part[0] = M; part[1] = den; }
    }

    // ---- signal completion; last block of batch b combines ----
    __threadfence();            // release: partial visible device-wide
    __syncthreads();
    if (tid == 0) sLast = (atomicAdd(&cnt[b], 1) == BLKPB - 1) ? 1 : 0;
    __syncthreads();
    if (sLast && tid < HIDD) {
        __threadfence();        // acquire: see all 32 partials
        const float* pb = partials + (size_t)b * BLKPB * PART_STRIDE;
        float M = -INFINITY;
#pragma unroll 8
        for (int c = 0; c < BLKPB; ++c) M = fmaxf(M, pb[c * PART_STRIDE]);
        float num = 0.f, den = 0.f;
#pragma unroll 8
        for (int c = 0; c < BLKPB; ++c) {
            float scale = __expf(pb[c * PART_STRIDE] - M);
            den += pb[c * PART_STRIDE + 1] * scale;
            num += pb[c * PART_STRIDE + 4 + tid] * scale;
        }
        out[b * HIDD + tid] = sC[tid] + num / den;
    }
}

extern "C" void kernel_launch(void* const* d_in, const int* in_sizes, int n_in,
                              void* d_out, int out_size, void* d_ws, size_t ws_size,
                              hipStream_t stream) {
    const float* cur  = (const float*)d_in[0];
    const float* hist = (const float*)d_in[1];
    const float* wxw  = (const float*)d_in[2];
    const float* wxb  = (const float*)d_in[3];
    const float* whw  = (const float*)d_in[4];
    const float* whb  = (const float*)d_in[5];
    const float* vw   = (const float*)d_in[6];
    float* out = (float*)d_out;

    // workspace: [partials 1024*132 f32][cnt 32 ints]
    float* partials = (float*)d_ws;
    int*   cnt      = (int*)((char*)d_ws + PART_BYTES);

    hipMemsetAsync(cnt, 0, BB * sizeof(int), stream);
    attn_fused_kernel<<<BB * BLKPB, 256, 0, stream>>>(
        hist, cur, whw, wxw, wxb, whb, vw, partials, cnt, out);
}

// Round 10
// 42.795 us; speedup vs baseline: 3.6078x; 3.6078x over previous
//
#include <hip/hip_runtime.h>
#include <hip/hip_bf16.h>

// Problem constants
#define BB     32
#define HIDD   128
#define ATT    128
#define SS     8192            // T*N positions per batch
#define BLKPB  32              // blocks per batch (256 rows each)
#define PART_STRIDE 132        // [den, pad, pad, pad, num[128]] (16B-aligned)

typedef float f32x4 __attribute__((ext_vector_type(4)));
typedef short s16x8 __attribute__((ext_vector_type(8)));

__device__ inline float bf2f(unsigned short h) {
    return __uint_as_float(((unsigned)h) << 16);
}
// tanh via exp; no clamp needed: v_exp handles +-inf -> r->0/1 correctly
__device__ inline float fast_tanh(float x) {
    float e2 = __expf(2.f * x);
    return 1.f - 2.f * __builtin_amdgcn_rcpf(e2 + 1.f);
}
__device__ inline unsigned cvt_pk_bf16(float a, float b) {
    unsigned r;
    asm("v_cvt_pk_bf16_f32 %0, %1, %2" : "=v"(r) : "v"(a), "v"(b));
    return r;   // low16 = bf16(a), high16 = bf16(b)
}

// ---- main: per block (b, blk of 256 rows). Stages W f32->bf16 (swizzled LDS)
//      and computes bias2 in-block (hidden under H tile-0 HBM latency), then
//      the proven zero-barrier loop: each wave owns 64 rows (4 tiles of 16),
//      single raw[8] prefetch buffer, swapped MFMA (bias in C-init), in-lane
//      v-dot, FIXED-MAX softmax (|score| <= 11.3 provably, so m == 0: no max
//      tracking, no rescale, no cross-tile dependency), accum from same regs.
// NOTE __launch_bounds__(256, 2): 2nd-arg VGPR cap is 256/arg on this backend
// (R4 arg2->128 ok; R5-7 arg4->64 + catastrophic spill).
__global__ __launch_bounds__(256, 2) void attn_main_kernel(
    const float* __restrict__ hist,
    const float* __restrict__ cur,
    const float* __restrict__ whw,
    const float* __restrict__ wxw,
    const float* __restrict__ wxb,
    const float* __restrict__ whb,
    const float* __restrict__ vw,
    float* __restrict__ partials)
{
    __shared__ __align__(16) unsigned short sW[ATT * HIDD];  // 32 KB bf16, swizzled
    __shared__ float sB[ATT];
    __shared__ float sV[ATT];
    __shared__ float sC[HIDD];
    __shared__ float sBp[2][ATT];
    __shared__ float sAccW[4][HIDD];   // per-wave merged output
    __shared__ float sL[4];

    const int tid  = threadIdx.x;
    const int bid  = blockIdx.x;
    const int b    = bid >> 5;          // /BLKPB
    const int blk  = bid & 31;
    const int lane = tid & 63;
    const int wid  = tid >> 6;
    const int l15  = lane & 15;
    const int lg   = lane >> 4;

    // wave's 64 rows
    const float* srcw = hist + ((size_t)b * SS + (size_t)blk * 256 + wid * 64) * HIDD;

    f32x4 raw[8];   // single in-flight tile (16 rows x 128 f32 / 64 lanes)
    auto issue = [&](int t) {
        const float* r = srcw + (size_t)(t * 16 + l15) * HIDD + lg * 8;
#pragma unroll
        for (int kk = 0; kk < 4; ++kk) {
            raw[2 * kk]     = *(const f32x4*)(r + kk * 32);
            raw[2 * kk + 1] = *(const f32x4*)(r + kk * 32 + 4);
        }
        __builtin_amdgcn_sched_barrier(0);   // pin issue point
    };

    issue(0);   // H tile-0 loads first: HBM head start

    // ---- stage W f32 -> bf16 (swizzled) ----
#pragma unroll
    for (int i = 0; i < 8; ++i) {
        int e = (i * 256 + tid) * 8;       // u16 index
        int row = e >> 7;
        f32x4 w0 = *(const f32x4*)(whw + e);
        f32x4 w1 = *(const f32x4*)(whw + e + 4);
        union { s16x8 v; unsigned w[4]; } o;
        o.w[0] = cvt_pk_bf16(w0.x, w0.y);
        o.w[1] = cvt_pk_bf16(w0.z, w0.w);
        o.w[2] = cvt_pk_bf16(w1.x, w1.y);
        o.w[3] = cvt_pk_bf16(w1.z, w1.w);
        *(s16x8*)&sW[e ^ ((row & 7) << 3)] = o.v;
    }
    if (tid < HIDD) { sC[tid] = cur[b * HIDD + tid]; sV[tid] = vw[tid]; }
    __syncthreads();

    // ---- bias2[a] = Wh_b + Wx_b + cur_h[b,:].Wx_w[a,:] (split over 2 halves) ----
    {
        const int a = tid & 127, half = tid >> 7;
        float d = 0.f;
#pragma unroll
        for (int hh = 0; hh < 16; ++hh) {
            f32x4 x = *(const f32x4*)(wxw + a * HIDD + half * 64 + hh * 4);
            f32x4 c = *(const f32x4*)&sC[half * 64 + hh * 4];
            d += x.x * c.x + x.y * c.y + x.z * c.z + x.w * c.w;
        }
        sBp[half][a] = d;
    }
    __syncthreads();
    if (tid < ATT) sB[tid] = sBp[0][tid] + sBp[1][tid] + wxb[tid] + whb[tid];
    __syncthreads();

    float lsum = 0.f;                       // per-lane: sum of e over own rows
    f32x4 acc[8];
#pragma unroll
    for (int q = 0; q < 8; ++q) acc[q] = (f32x4){0.f, 0.f, 0.f, 0.f};

#pragma unroll
    for (int t = 0; t < 4; ++t) {
        // ---- cvt raw -> bf16 frags (auto-waits this tile's loads) ----
        s16x8 hfrag[4];
#pragma unroll
        for (int kk = 0; kk < 4; ++kk) {
            union { s16x8 v; unsigned w[4]; } fr;
            fr.w[0] = cvt_pk_bf16(raw[2 * kk].x,     raw[2 * kk].y);
            fr.w[1] = cvt_pk_bf16(raw[2 * kk].z,     raw[2 * kk].w);
            fr.w[2] = cvt_pk_bf16(raw[2 * kk + 1].x, raw[2 * kk + 1].y);
            fr.w[3] = cvt_pk_bf16(raw[2 * kk + 1].z, raw[2 * kk + 1].w);
            hfrag[kk] = fr.v;
        }
        // ---- re-issue next tile into the SAME raw regs (async) ----
        if (t < 3) issue(t + 1);

        // ---- scores: 8 a-tiles, D[a][s] = W . H^T + bias (C-init), v-dot in-lane ----
        float p = 0.f;
#pragma unroll
        for (int at = 0; at < 8; ++at) {
            s16x8 wfrag[4];
#pragma unroll
            for (int kk = 0; kk < 4; ++kk) {
                int idx = ((at * 16 + l15) * HIDD + kk * 32 + lg * 8) ^ ((l15 & 7) << 3);
                wfrag[kk] = *(const s16x8*)&sW[idx];
            }
            f32x4 d = *(const f32x4*)&sB[at * 16 + lg * 4];   // bias as C-init
#pragma unroll
            for (int kk = 0; kk < 4; ++kk)
                d = __builtin_amdgcn_mfma_f32_16x16x32_bf16(wfrag[kk], hfrag[kk], d, 0, 0, 0);
            f32x4 vx = *(const f32x4*)&sV[at * 16 + lg * 4];
#pragma unroll
            for (int r = 0; r < 4; ++r)
                p += vx[r] * fast_tanh(d[r]);
        }
        p += __shfl_xor(p, 16, 64);
        p += __shfl_xor(p, 32, 64);   // all lanes: score for row = l15

        // ---- fixed-max softmax: |p| <= sum|v| <= 11.32 -> e^p in [1e-5, 8e4] ----
        float ev = __expf(p);
        lsum += ev;                    // rows replicated across lg; fixed later

        // ---- weighted accumulation from the SAME frags (H touched once) ----
#pragma unroll
        for (int kk = 0; kk < 4; ++kk) {
            union { s16x8 v; unsigned short u[8]; } fr; fr.v = hfrag[kk];
#pragma unroll
            for (int i = 0; i < 4; ++i) acc[2 * kk][i]     += ev * bf2f(fr.u[i]);
#pragma unroll
            for (int i = 0; i < 4; ++i) acc[2 * kk + 1][i] += ev * bf2f(fr.u[4 + i]);
        }
    }

    // ---- reduce acc + lsum over the 16 s-lanes (within each 16-lane group) ----
#pragma unroll
    for (int m = 1; m < 16; m <<= 1) {
        lsum += __shfl_xor(lsum, m, 64);
#pragma unroll
        for (int q = 0; q < 8; ++q) {
#pragma unroll
            for (int i = 0; i < 4; ++i)
                acc[q][i] += __shfl_xor(acc[q][i], m, 64);
        }
    }
    // lanes l15==0 (lg = 0..3) hold h[k] for k = kk*32 + lg*8 + i
    if (l15 == 0) {
#pragma unroll
        for (int kk = 0; kk < 4; ++kk) {
            *(f32x4*)&sAccW[wid][kk * 32 + lg * 8]     = acc[2 * kk];
            *(f32x4*)&sAccW[wid][kk * 32 + lg * 8 + 4] = acc[2 * kk + 1];
        }
    }
    if (lane == 0) sL[wid] = lsum;     // lsum identical across lg groups
    __syncthreads();

    // ---- merge 4 waves, write block partial [den, num[128]] ----
    if (tid < HIDD) {
        float num = sAccW[0][tid] + sAccW[1][tid] + sAccW[2][tid] + sAccW[3][tid];
        float* part = partials + (size_t)(b * BLKPB + blk) * PART_STRIDE;
        part[4 + tid] = num;
        if (tid == 0) part[0] = sL[0] + sL[1] + sL[2] + sL[3];
    }
}

// ---- combine: out = cur + (sum num) / (sum den) ----
__global__ void attn_combine_kernel(const float* __restrict__ cur,
                                    const float* __restrict__ partials,
                                    float* __restrict__ out)
{
    int b = blockIdx.x, h = threadIdx.x;   // 128 threads
    const float* pb = partials + (size_t)b * BLKPB * PART_STRIDE;
    float num = 0.f, den = 0.f;
#pragma unroll 8
    for (int c = 0; c < BLKPB; ++c) {
        den += pb[c * PART_STRIDE];
        num += pb[c * PART_STRIDE + 4 + h];
    }
    out[b * HIDD + h] = cur[b * HIDD + h] + num / den;
}

extern "C" void kernel_launch(void* const* d_in, const int* in_sizes, int n_in,
                              void* d_out, int out_size, void* d_ws, size_t ws_size,
                              hipStream_t stream) {
    const float* cur  = (const float*)d_in[0];
    const float* hist = (const float*)d_in[1];
    const float* wxw  = (const float*)d_in[2];
    const float* wxb  = (const float*)d_in[3];
    const float* whw  = (const float*)d_in[4];
    const float* whb  = (const float*)d_in[5];
    const float* vw   = (const float*)d_in[6];
    float* out = (float*)d_out;

    float* partials = (float*)d_ws;   // 1024 * 132 f32

    attn_main_kernel<<<BB * BLKPB, 256, 0, stream>>>(
        hist, cur, whw, wxw, wxb, whb, vw, partials);
    attn_combine_kernel<<<BB, HIDD, 0, stream>>>(cur, partials, out);
}

// Round 11
// 41.379 us; speedup vs baseline: 3.7312x; 1.0342x over previous
//
#include <hip/hip_runtime.h>
#include <hip/hip_bf16.h>

// Problem constants
#define BB     32
#define HIDD   128
#define ATT    128
#define SS     8192            // T*N positions per batch
#define BLKPB  32              // blocks per batch (256 rows each)
#define PART_STRIDE 132        // [den, pad, pad, pad, num[128]] (16B-aligned)

typedef float f32x4 __attribute__((ext_vector_type(4)));
typedef short s16x8 __attribute__((ext_vector_type(8)));

__device__ inline float bf2f(unsigned short h) {
    return __uint_as_float(((unsigned)h) << 16);
}
// tanh via exp; no clamp needed: v_exp handles +-inf -> r->0/1 correctly
__device__ inline float fast_tanh(float x) {
    float e2 = __expf(2.f * x);
    return 1.f - 2.f * __builtin_amdgcn_rcpf(e2 + 1.f);
}
__device__ inline unsigned cvt_pk_bf16(float a, float b) {
    unsigned r;
    asm("v_cvt_pk_bf16_f32 %0, %1, %2" : "=v"(r) : "v"(a), "v"(b));
    return r;   // low16 = bf16(a), high16 = bf16(b)
}

// ---- main: per block (b, blk of 256 rows). Stages W f32->bf16 (swizzled LDS)
//      and computes bias2 in-block (hidden under H tile-0 HBM latency), then
//      the proven zero-barrier loop: each wave owns 64 rows (4 tiles of 16),
//      single raw[8] prefetch buffer, swapped MFMA (bias in C-init), in-lane
//      v-dot, fixed-max softmax (|score| <= 11.3 provably), accum from the
//      same regs.
// Swizzle: full (row&15)<<3 XOR on u16 index — spreads the wfrag b128 read
//      uniformly (4 lanes per 16B-unit = the b128 bank floor); (row&7) only
//      used 8 of 16 units -> 8 lanes/unit -> the 1.57M conflicts seen in R10.
// NOTE __launch_bounds__(256, 2): 2nd-arg VGPR cap is 256/arg on this backend
// (R4 arg2->128 ok; R5-7 arg4->64 + catastrophic spill).
__global__ __launch_bounds__(256, 2) void attn_main_kernel(
    const float* __restrict__ hist,
    const float* __restrict__ cur,
    const float* __restrict__ whw,
    const float* __restrict__ wxw,
    const float* __restrict__ wxb,
    const float* __restrict__ whb,
    const float* __restrict__ vw,
    float* __restrict__ partials)
{
    __shared__ __align__(16) unsigned short sW[ATT * HIDD];  // 32 KB bf16, swizzled
    __shared__ float sB[ATT];
    __shared__ float sV[ATT];
    __shared__ float sC[HIDD];
    __shared__ float sBp[2][ATT];
    __shared__ float sAccW[4][HIDD];   // per-wave merged output
    __shared__ float sL[4];

    const int tid  = threadIdx.x;
    const int bid  = blockIdx.x;
    const int b    = bid >> 5;          // /BLKPB
    const int blk  = bid & 31;
    const int lane = tid & 63;
    const int wid  = tid >> 6;
    const int l15  = lane & 15;
    const int lg   = lane >> 4;

    // wave's 64 rows
    const float* srcw = hist + ((size_t)b * SS + (size_t)blk * 256 + wid * 64) * HIDD;

    f32x4 raw[8];   // single in-flight tile (16 rows x 128 f32 / 64 lanes)
    auto issue = [&](int t) {
        const float* r = srcw + (size_t)(t * 16 + l15) * HIDD + lg * 8;
#pragma unroll
        for (int kk = 0; kk < 4; ++kk) {
            raw[2 * kk]     = *(const f32x4*)(r + kk * 32);
            raw[2 * kk + 1] = *(const f32x4*)(r + kk * 32 + 4);
        }
        __builtin_amdgcn_sched_barrier(0);   // pin issue point
    };

    issue(0);   // H tile-0 loads first: HBM head start

    // ---- stage W f32 -> bf16 (swizzled: full row&15) ----
#pragma unroll
    for (int i = 0; i < 8; ++i) {
        int e = (i * 256 + tid) * 8;       // u16 index
        int row = e >> 7;
        f32x4 w0 = *(const f32x4*)(whw + e);
        f32x4 w1 = *(const f32x4*)(whw + e + 4);
        union { s16x8 v; unsigned w[4]; } o;
        o.w[0] = cvt_pk_bf16(w0.x, w0.y);
        o.w[1] = cvt_pk_bf16(w0.z, w0.w);
        o.w[2] = cvt_pk_bf16(w1.x, w1.y);
        o.w[3] = cvt_pk_bf16(w1.z, w1.w);
        *(s16x8*)&sW[e ^ ((row & 15) << 3)] = o.v;
    }
    if (tid < HIDD) { sC[tid] = cur[b * HIDD + tid]; sV[tid] = vw[tid]; }
    __syncthreads();

    // ---- bias2[a] = Wh_b + Wx_b + cur_h[b,:].Wx_w[a,:] (split over 2 halves) ----
    {
        const int a = tid & 127, half = tid >> 7;
        float d = 0.f;
#pragma unroll
        for (int hh = 0; hh < 16; ++hh) {
            f32x4 x = *(const f32x4*)(wxw + a * HIDD + half * 64 + hh * 4);
            f32x4 c = *(const f32x4*)&sC[half * 64 + hh * 4];
            d += x.x * c.x + x.y * c.y + x.z * c.z + x.w * c.w;
        }
        sBp[half][a] = d;
    }
    __syncthreads();
    if (tid < ATT) sB[tid] = sBp[0][tid] + sBp[1][tid] + wxb[tid] + whb[tid];
    __syncthreads();

    float lsum = 0.f;                       // per-lane: sum of e over own rows
    f32x4 acc[8];
#pragma unroll
    for (int q = 0; q < 8; ++q) acc[q] = (f32x4){0.f, 0.f, 0.f, 0.f};

#pragma unroll
    for (int t = 0; t < 4; ++t) {
        // ---- cvt raw -> bf16 frags (auto-waits this tile's loads) ----
        s16x8 hfrag[4];
#pragma unroll
        for (int kk = 0; kk < 4; ++kk) {
            union { s16x8 v; unsigned w[4]; } fr;
            fr.w[0] = cvt_pk_bf16(raw[2 * kk].x,     raw[2 * kk].y);
            fr.w[1] = cvt_pk_bf16(raw[2 * kk].z,     raw[2 * kk].w);
            fr.w[2] = cvt_pk_bf16(raw[2 * kk + 1].x, raw[2 * kk + 1].y);
            fr.w[3] = cvt_pk_bf16(raw[2 * kk + 1].z, raw[2 * kk + 1].w);
            hfrag[kk] = fr.v;
        }
        // ---- re-issue next tile into the SAME raw regs (async) ----
        if (t < 3) issue(t + 1);

        // ---- scores: 8 a-tiles, D[a][s] = W . H^T + bias (C-init), v-dot in-lane ----
        float p = 0.f;
#pragma unroll
        for (int at = 0; at < 8; ++at) {
            s16x8 wfrag[4];
#pragma unroll
            for (int kk = 0; kk < 4; ++kk) {
                int idx = ((at * 16 + l15) * HIDD + kk * 32 + lg * 8) ^ ((l15 & 15) << 3);
                wfrag[kk] = *(const s16x8*)&sW[idx];
            }
            f32x4 d = *(const f32x4*)&sB[at * 16 + lg * 4];   // bias as C-init
            __builtin_amdgcn_s_setprio(1);
#pragma unroll
            for (int kk = 0; kk < 4; ++kk)
                d = __builtin_amdgcn_mfma_f32_16x16x32_bf16(wfrag[kk], hfrag[kk], d, 0, 0, 0);
            __builtin_amdgcn_s_setprio(0);
            f32x4 vx = *(const f32x4*)&sV[at * 16 + lg * 4];
#pragma unroll
            for (int r = 0; r < 4; ++r)
                p += vx[r] * fast_tanh(d[r]);
        }
        p += __shfl_xor(p, 16, 64);
        p += __shfl_xor(p, 32, 64);   // all lanes: score for row = l15

        // ---- fixed-max softmax: |p| <= sum|v| <= 11.32 -> e^p in [1e-5, 8e4] ----
        float ev = __expf(p);
        lsum += ev;                    // rows replicated across lg; fixed later

        // ---- weighted accumulation from the SAME frags (H touched once) ----
#pragma unroll
        for (int kk = 0; kk < 4; ++kk) {
            union { s16x8 v; unsigned short u[8]; } fr; fr.v = hfrag[kk];
#pragma unroll
            for (int i = 0; i < 4; ++i) acc[2 * kk][i]     += ev * bf2f(fr.u[i]);
#pragma unroll
            for (int i = 0; i < 4; ++i) acc[2 * kk + 1][i] += ev * bf2f(fr.u[4 + i]);
        }
    }

    // ---- reduce acc + lsum over the 16 s-lanes (within each 16-lane group) ----
#pragma unroll
    for (int m = 1; m < 16; m <<= 1) {
        lsum += __shfl_xor(lsum, m, 64);
#pragma unroll
        for (int q = 0; q < 8; ++q) {
#pragma unroll
            for (int i = 0; i < 4; ++i)
                acc[q][i] += __shfl_xor(acc[q][i], m, 64);
        }
    }
    // lanes l15==0 (lg = 0..3) hold h[k] for k = kk*32 + lg*8 + i
    if (l15 == 0) {
#pragma unroll
        for (int kk = 0; kk < 4; ++kk) {
            *(f32x4*)&sAccW[wid][kk * 32 + lg * 8]     = acc[2 * kk];
            *(f32x4*)&sAccW[wid][kk * 32 + lg * 8 + 4] = acc[2 * kk + 1];
        }
    }
    if (lane == 0) sL[wid] = lsum;     // lsum identical across lg groups
    __syncthreads();

    // ---- merge 4 waves, write block partial [den, num[128]] ----
    if (tid < HIDD) {
        float num = sAccW[0][tid] + sAccW[1][tid] + sAccW[2][tid] + sAccW[3][tid];
        float* part = partials + (size_t)(b * BLKPB + blk) * PART_STRIDE;
        part[4 + tid] = num;
        if (tid == 0) part[0] = sL[0] + sL[1] + sL[2] + sL[3];
    }
}

// ---- combine: out = cur + (sum num) / (sum den) ----
__global__ void attn_combine_kernel(const float* __restrict__ cur,
                                    const float* __restrict__ partials,
                                    float* __restrict__ out)
{
    int b = blockIdx.x, h = threadIdx.x;   // 128 threads
    const float* pb = partials + (size_t)b * BLKPB * PART_STRIDE;
    float num = 0.f, den = 0.f;
#pragma unroll 8
    for (int c = 0; c < BLKPB; ++c) {
        den += pb[c * PART_STRIDE];
        num += pb[c * PART_STRIDE + 4 + h];
    }
    out[b * HIDD + h] = cur[b * HIDD + h] + num / den;
}

extern "C" void kernel_launch(void* const* d_in, const int* in_sizes, int n_in,
                              void* d_out, int out_size, void* d_ws, size_t ws_size,
                              hipStream_t stream) {
    const float* cur  = (const float*)d_in[0];
    const float* hist = (const float*)d_in[1];
    const float* wxw  = (const float*)d_in[2];
    const float* wxb  = (const float*)d_in[3];
    const float* whw  = (const float*)d_in[4];
    const float* whb  = (const float*)d_in[5];
    const float* vw   = (const float*)d_in[6];
    float* out = (float*)d_out;

    float* partials = (float*)d_ws;   // 1024 * 132 f32

    attn_main_kernel<<<BB * BLKPB, 256, 0, stream>>>(
        hist, cur, whw, wxw, wxb, whb, vw, partials);
    attn_combine_kernel<<<BB, HIDD, 0, stream>>>(cur, partials, out);
}